// Round 5
// baseline (956.830 us; speedup 1.0000x reference)
//
#include <hip/hip_runtime.h>
#include <stdint.h>

typedef _Float16 half8 __attribute__((ext_vector_type(8)));
typedef float float4v __attribute__((ext_vector_type(4)));

__host__ __device__ inline void tf2x32(uint32_t k0, uint32_t k1,
                                       uint32_t x0, uint32_t x1,
                                       uint32_t* o0, uint32_t* o1) {
  const uint32_t ks2 = k0 ^ k1 ^ 0x1BD11BDAu;
#define ROTL(v, s) (((v) << (s)) | ((v) >> (32 - (s))))
#define RND(r) do { x0 += x1; x1 = ROTL(x1, r); x1 ^= x0; } while (0)
  x0 += k0; x1 += k1;
  RND(13); RND(15); RND(26); RND(6);
  x0 += k1; x1 += ks2 + 1u;
  RND(17); RND(29); RND(16); RND(24);
  x0 += ks2; x1 += k0 + 2u;
  RND(13); RND(15); RND(26); RND(6);
  x0 += k0; x1 += k1 + 3u;
  RND(17); RND(29); RND(16); RND(24);
  x0 += k1; x1 += ks2 + 4u;
  RND(13); RND(15); RND(26); RND(6);
  x0 += ks2; x1 += k0 + 5u;
  *o0 = x0; *o1 = x1;
#undef RND
#undef ROTL
}

__device__ inline bool drop_keep(uint32_t k0, uint32_t k1, uint32_t idx) {
  uint32_t o0, o1;
  tf2x32(k0, k1, 0u, idx, &o0, &o1);
  uint32_t bits = o0 ^ o1;
  float u = __uint_as_float((bits >> 9) | 0x3f800000u) - 1.0f;
  return u < 0.4f;
}

// Grid-wide barrier for a co-resident grid (grid <= 8 blocks/CU x 256 CU,
// guaranteed by __launch_bounds__(256,8) + grid 1568). Counter zeroed by the
// host memsetAsync each iteration. Agent-scope ACQ_REL RMW on arrival emits
// the L2 writeback (release) making this XCD's dirty lines visible at the
// coherence point; after the spin, an agent acquire fence invalidates
// L1/L2 so post-barrier reads can't see stale lines (replaces the cache
// maintenance kernel boundaries used to provide).
__device__ __forceinline__ void grid_bar(unsigned* ctr, unsigned target) {
  __syncthreads();                  // block stores drained (vmcnt before s_barrier)
  if (threadIdx.x == 0) {
    __hip_atomic_fetch_add(ctr, 1u, __ATOMIC_ACQ_REL, __HIP_MEMORY_SCOPE_AGENT);
    while (__hip_atomic_load(ctr, __ATOMIC_RELAXED, __HIP_MEMORY_SCOPE_AGENT) < target)
      __builtin_amdgcn_s_sleep(2);
    __builtin_amdgcn_fence(__ATOMIC_ACQUIRE, "agent");
  }
  __syncthreads();
}

// One batch-group of T*8 edges starting at slot jb*8: issue T half8 loads,
// then consume into acc in ascending-j order (same FP order as R14/R17).
// Lane l = 8*g + sub loads bytes [sub*16, sub*16+16) of edge (jb+j)*8+g's row.
// T capped at 4 so register peak fits the 64-VGPR cap (R15 lesson).
template<int T>
__device__ __forceinline__ void gatherT(int idx_all, int rnd, int jb, int g,
                                        int sub,
                                        const _Float16* __restrict__ ysg,
                                        uint32_t dummy, float acc[8]) {
  half8 hv[T];
  #pragma unroll
  for (int j = 0; j < T; ++j) {
    int sh = __shfl(idx_all, (jb + j) * 8 + g, 64);
    uint32_t c = ((jb + j) * 8 < rnd) ? (uint32_t)(sh & 0xffff) : dummy;
    hv[j] = *(const half8*)((const char*)ysg + (c << 7) + (sub << 4));
  }
  #pragma unroll
  for (int j = 0; j < T; ++j)
    #pragma unroll
    for (int k = 0; k < 8; ++k) acc[k] += (float)hv[j][k];
}

// Conv phase (R17 k_conv body, verbatim numerics), looped over virtual
// tiles vb = bid, bid+G, ... (max 2 iterations at G=1568). Trailing
// __syncthreads protects xp reuse across iterations.
template<int COUT, bool RELU, bool DROPN, bool WBF>
__device__ __forceinline__ void conv_phase(
    _Float16 (*xp)[136],
    const _Float16* __restrict__ yg, const _Float16* __restrict__ ysg,
    const int* __restrict__ cnt, const uint16_t* __restrict__ cs,
    const float* __restrict__ dis, const _Float16* __restrict__ wt,
    const float* __restrict__ b, float* __restrict__ outf,
    _Float16* __restrict__ outb, _Float16* __restrict__ outs,
    uint32_t nk0, uint32_t nk1, int n, int ntiles) {
  const int wave = threadIdx.x >> 6;
  const int t    = threadIdx.x & 63;
  const int g    = t >> 3;
  const int sub  = t & 7;
  const uint32_t dummy = (uint32_t)n;

  for (int vb = blockIdx.x; vb < ntiles; vb += (int)gridDim.x) {
    const int row0 = vb * 16;

    // ---- Phase 1 prologue: all 4 rows' loads issued up front ----
    int      idxs[4], ds4[4];
    float    dv4[4];
    _Float16 ygv[4];
    #pragma unroll
    for (int i = 0; i < 4; ++i) {
      int r = row0 + wave * 4 + i;
      r = r < n ? r : n - 1;
      idxs[i] = cs[(r << 6) + t];
      ds4[i]  = cnt[r];
      dv4[i]  = dis[r];
      ygv[i]  = yg[(uint32_t)(r << 6) + t];
    }

    // ---- Phase 1: per-row gather + butterfly reduction ----
    #pragma unroll
    for (int i = 0; i < 4; ++i) {
      const int cn  = ds4[i] < 64 ? ds4[i] : 64;
      const int rnd = (cn + 7) & ~7;
      float acc[8] = {0.f, 0.f, 0.f, 0.f, 0.f, 0.f, 0.f, 0.f};
      if (rnd <= 16) {
        gatherT<2>(idxs[i], rnd, 0, g, sub, ysg, dummy, acc);
      } else if (rnd <= 32) {
        gatherT<4>(idxs[i], rnd, 0, g, sub, ysg, dummy, acc);
      } else {
        gatherT<4>(idxs[i], rnd, 0, g, sub, ysg, dummy, acc);
        gatherT<4>(idxs[i], rnd, 4, g, sub, ysg, dummy, acc);
      }

      const bool b0 = (g & 1), b1 = (g & 2), b2 = (g & 4);
      float a4[4], a2[2], v;
      #pragma unroll
      for (int m = 0; m < 4; ++m) {
        float keep = b0 ? acc[2 * m + 1] : acc[2 * m];
        float send = b0 ? acc[2 * m]     : acc[2 * m + 1];
        a4[m] = keep + __shfl_xor(send, 8, 64);
      }
      #pragma unroll
      for (int m = 0; m < 2; ++m) {
        float keep = b1 ? a4[2 * m + 1] : a4[2 * m];
        float send = b1 ? a4[2 * m]     : a4[2 * m + 1];
        a2[m] = keep + __shfl_xor(send, 16, 64);
      }
      {
        float keep = b2 ? a2[1] : a2[0];
        float send = b2 ? a2[0] : a2[1];
        v = keep + __shfl_xor(send, 32, 64);
      }
      const int rl = wave * 4 + i;
      xp[rl][t]                  = ygv[i];
      xp[rl][64 + (sub * 8 + g)] = (_Float16)(-dv4[i] * v);
    }
    __syncthreads();

    // ---- Phase 2: MFMA (B fragments from global W^T) ----
    constexpr int NW = COUT / 16;
    const int nn   = t & 15;
    const int quad = t >> 4;
    if (wave < NW) {
      const int colg = wave * 16 + nn;
      float4v acc = {0.f, 0.f, 0.f, 0.f};
      #pragma unroll
      for (int ks = 0; ks < 4; ++ks) {
        half8 a  = *(const half8*)&xp[nn][quad * 8 + 32 * ks];
        half8 bb = *(const half8*)&wt[(size_t)colg * 128 + quad * 8 + 32 * ks];
        acc = __builtin_amdgcn_mfma_f32_16x16x32_f16(a, bb, acc, 0, 0, 0);
      }
      // ---- Phase 3: epilogue ----
      const float bias = b[colg];
      #pragma unroll
      for (int rg = 0; rg < 4; ++rg) {
        const int rl = quad * 4 + rg;
        const int rr = row0 + rl;
        if (rr < n) {
          float v = acc[rg] + bias;
          if (RELU) v = fmaxf(v, 0.0f);
          if (DROPN) {
            if (drop_keep(nk0, nk1, (uint32_t)(rr * 64 + colg))) v *= 2.5f;
            else v = 0.0f;
          }
          if (WBF) {
            outb[(size_t)rr * COUT + colg] = (_Float16)v;
            outs[(size_t)rr * COUT + colg] = (_Float16)(dis[rr] * v);
          } else {
            outf[(size_t)rr * COUT + colg] = v;
          }
        }
      }
    }
    __syncthreads();   // xp reused next virtual tile
  }
}

// R19: single persistent kernel — fill + drop + 3 convs with 4 grid
// barriers, removing 5 inter-dispatch boundaries (~50-60us of the 190us
// total per the R14/R18 accounting). Grid 1568 x 256, launch_bounds(256,8):
// VGPR<=64 -> 8 blocks/CU capacity (2048) -> co-residency guaranteed.
// 1568%8==0 keeps the fill phase's vb%8 == physical-XCD mapping; conv's
// 3125 tiles / 1568 -> max 2 tiles/block (0.4% imbalance).
__global__ __launch_bounds__(256, 8) void k_fused(
    const float* __restrict__ x, const int* __restrict__ row,
    const int* __restrict__ col,
    const float* __restrict__ W0, const float* __restrict__ b0,
    const float* __restrict__ W1, const float* __restrict__ b1,
    const float* __restrict__ W2, const float* __restrict__ b2,
    unsigned* __restrict__ bars, int* __restrict__ cnt,
    float* __restrict__ dis, uint16_t* __restrict__ cs,
    _Float16* __restrict__ ya, _Float16* __restrict__ ysa,
    _Float16* __restrict__ yb, _Float16* __restrict__ ysb,
    _Float16* __restrict__ wh, float* __restrict__ out,
    uint32_t dk00, uint32_t dk01, uint32_t dk10, uint32_t dk11,
    uint32_t dk20, uint32_t dk21, int n, int e) {
  __shared__ __align__(16) _Float16 xp[16][136];
  const int tid  = threadIdx.x;
  const int bid  = blockIdx.x;
  const int G    = (int)gridDim.x;
  const int gtid = bid * 256 + tid;
  const unsigned tgt = gridDim.x;

  // ---- P0 (no deps; overlaps fill): W -> f16 W^T + zero dummy gather rows
  if (gtid < 20480) {
    int d = gtid;
    if (d < 8192) {
      int o = d >> 7, k = d & 127;
      wh[d] = (_Float16)W0[k * 64 + o];
    } else if (d < 16384) {
      int d1 = d - 8192, o = d1 >> 7, k = d1 & 127;
      wh[d] = (_Float16)W1[k * 64 + o];
    } else {
      int d2 = d - 16384, o = d2 >> 7, k = d2 & 127;
      wh[d] = (_Float16)W2[k * 32 + o];
    }
  }
  if (gtid < 64) {
    ysa[((size_t)n << 6) + gtid] = (_Float16)0.f;
    ysb[((size_t)n << 6) + gtid] = (_Float16)0.f;
  }

  // ---- P1: XCD-owned slotted-CSR fill (cnt zeroed by host memsetAsync)
  {
    const int rpx = (n + 7) / 8;
    const int nc8 = ((e + 255) >> 8) * 8;
    for (int vb = bid; vb < nc8; vb += G) {
      const int owner = vb & 7;                 // == physical XCD (G%8==0)
      const int i = (vb >> 3) * 256 + tid;
      if (i < e) {
        int r = row[i];
        if (r / rpx == owner) {
          int pos = atomicAdd(&cnt[r], 1);
          if (pos < 64) cs[(r << 6) + pos] = (uint16_t)col[i];
        }
      }
    }
  }
  grid_bar(&bars[0], tgt);

  // ---- P2: layer-0 dropout + dis + slot padding
  {
    const int nd = n * 64;
    for (int i = gtid; i < nd; i += G * 256) {
      const int r  = i >> 6;
      const int t2 = i & 63;
      const int d  = cnt[r];
      const float dis_r = (d > 0) ? rsqrtf((float)d) : 0.0f;
      float v = drop_keep(dk00, dk01, (uint32_t)i) ? x[i] * 2.5f : 0.0f;
      ya[i]  = (_Float16)v;
      ysa[i] = (_Float16)(dis_r * v);
      if (t2 == 0) dis[r] = dis_r;
      const int cn  = d < 64 ? d : 64;
      const int rnd = (cn + 7) & ~7;
      if (t2 >= cn && t2 < rnd) cs[(r << 6) + t2] = (uint16_t)n;
    }
  }
  grid_bar(&bars[1], tgt);

  // ---- P3..P5: the three conv layers
  const int ntiles = (n + 15) / 16;
  conv_phase<64, true,  true,  true >(xp, ya, ysa, cnt, cs, dis, wh, b0,
                                      nullptr, yb, ysb, dk10, dk11, n, ntiles);
  grid_bar(&bars[2], tgt);
  conv_phase<64, true,  true,  true >(xp, yb, ysb, cnt, cs, dis, wh + 8192, b1,
                                      nullptr, ya, ysa, dk20, dk21, n, ntiles);
  grid_bar(&bars[3], tgt);
  conv_phase<32, false, false, false>(xp, ya, ysa, cnt, cs, dis, wh + 16384, b2,
                                      out, nullptr, nullptr, 0u, 0u, n, ntiles);
}

extern "C" void kernel_launch(void* const* d_in, const int* in_sizes, int n_in,
                              void* d_out, int out_size, void* d_ws, size_t ws_size,
                              hipStream_t stream) {
  const float* x   = (const float*)d_in[0];
  const int*   ei  = (const int*)d_in[1];
  const float* W0  = (const float*)d_in[2];
  const float* b0  = (const float*)d_in[3];
  const float* W1f = (const float*)d_in[4];
  const float* b1  = (const float*)d_in[5];
  const float* W2  = (const float*)d_in[6];
  const float* b2  = (const float*)d_in[7];
  float* out = (float*)d_out;

  const int n = in_sizes[0] / 64;   // 50000
  const int e = in_sizes[1] / 2;    // 800000
  const int* row = ei;
  const int* col = ei + e;

  size_t off = 0;
  auto carve = [&](size_t elems) {   // elems in int32 units, 1KB-aligned
    size_t o = off;
    off += (elems + 255) & ~(size_t)255;
    return o;
  };
  int* base = (int*)d_ws;
  unsigned* bars = (unsigned*)(base + carve(8));                   // [0,256) ints
  int*      cnt  = base + carve(n);                                // at 256
  float*    dis  = (float*)(base + carve(n));
  uint16_t* cs   = (uint16_t*)(base + carve((size_t)n * 32));      // n*64 u16
  _Float16* ya   = (_Float16*)(base + carve((size_t)n * 32));      // n*64 f16
  _Float16* ysa  = (_Float16*)(base + carve((size_t)(n + 1) * 32));
  _Float16* yb   = (_Float16*)(base + carve((size_t)n * 32));
  _Float16* ysb  = (_Float16*)(base + carve((size_t)(n + 1) * 32));
  _Float16* wh   = (_Float16*)(base + carve(10240));               // 20480 f16
  (void)ws_size;

  // dropout keys: fold_in(jax.random.key(1), i) = threefry2x32([0,1],[0,i])
  uint32_t dk[3][2];
  for (uint32_t i = 0; i < 3; ++i) tf2x32(0u, 1u, 0u, i, &dk[i][0], &dk[i][1]);

  // zero barrier counters (first 1KB) AND cnt in one contiguous memset
  hipMemsetAsync(base, 0, (size_t)(256 + n) * 4, stream);

  const int G = 1568;   // co-resident at 8 blocks/CU; %8==0; ceil(3125/G)=2
  k_fused<<<G, 256, 0, stream>>>(x, row, col, W0, b0, W1f, b1, W2, b2,
                                 bars, cnt, dis, cs, ya, ysa, yb, ysb, wh, out,
                                 dk[0][0], dk[0][1], dk[1][0], dk[1][1],
                                 dk[2][0], dk[2][1], n, e);
}

// Round 6
// 769.193 us; speedup vs baseline: 1.2439x; 1.2439x over previous
//
#include <hip/hip_runtime.h>
#include <stdint.h>

typedef _Float16 half8 __attribute__((ext_vector_type(8)));
typedef float float4v __attribute__((ext_vector_type(4)));

__host__ __device__ inline void tf2x32(uint32_t k0, uint32_t k1,
                                       uint32_t x0, uint32_t x1,
                                       uint32_t* o0, uint32_t* o1) {
  const uint32_t ks2 = k0 ^ k1 ^ 0x1BD11BDAu;
#define ROTL(v, s) (((v) << (s)) | ((v) >> (32 - (s))))
#define RND(r) do { x0 += x1; x1 = ROTL(x1, r); x1 ^= x0; } while (0)
  x0 += k0; x1 += k1;
  RND(13); RND(15); RND(26); RND(6);
  x0 += k1; x1 += ks2 + 1u;
  RND(17); RND(29); RND(16); RND(24);
  x0 += ks2; x1 += k0 + 2u;
  RND(13); RND(15); RND(26); RND(6);
  x0 += k0; x1 += k1 + 3u;
  RND(17); RND(29); RND(16); RND(24);
  x0 += k1; x1 += ks2 + 4u;
  RND(13); RND(15); RND(26); RND(6);
  x0 += ks2; x1 += k0 + 5u;
  *o0 = x0; *o1 = x1;
#undef RND
#undef ROTL
}

__device__ inline bool drop_keep(uint32_t k0, uint32_t k1, uint32_t idx) {
  uint32_t o0, o1;
  tf2x32(k0, k1, 0u, idx, &o0, &o1);
  uint32_t bits = o0 ^ o1;
  float u = __uint_as_float((bits >> 9) | 0x3f800000u) - 1.0f;
  return u < 0.4f;
}

// Grid-wide barrier for a co-resident grid (grid <= 4 blocks/CU x 256 CU,
// guaranteed by __launch_bounds__(256,4) + grid 1024). Counters zeroed by
// the host memsetAsync each iteration. Agent-scope ACQ_REL RMW on arrival
// publishes this XCD's dirty L2 lines at the coherence point; after the
// spin, an agent acquire fence invalidates L1/L2 before any post-barrier
// reads (executed by ALL waves after release — R19 fenced only lane 0).
__device__ __forceinline__ void grid_bar(unsigned* ctr, unsigned target) {
  __syncthreads();                  // block stores drained (vmcnt before s_barrier)
  if (threadIdx.x == 0) {
    __hip_atomic_fetch_add(ctr, 1u, __ATOMIC_ACQ_REL, __HIP_MEMORY_SCOPE_AGENT);
    while (__hip_atomic_load(ctr, __ATOMIC_RELAXED, __HIP_MEMORY_SCOPE_AGENT) < target)
      __builtin_amdgcn_s_sleep(2);
  }
  __syncthreads();
  __builtin_amdgcn_fence(__ATOMIC_ACQUIRE, "agent");
}

// One batch-group of T*8 edges starting at slot jb*8: issue T half8 loads,
// then consume into acc in ascending-j order (same FP order as R14/R17).
// Lane l = 8*g + sub loads bytes [sub*16, sub*16+16) of edge (jb+j)*8+g's row.
// T capped at 4: 16-VGPR staging window (R15/R19 spill lesson).
template<int T>
__device__ __forceinline__ void gatherT(int idx_all, int rnd, int jb, int g,
                                        int sub,
                                        const _Float16* __restrict__ ysg,
                                        uint32_t dummy, float acc[8]) {
  half8 hv[T];
  #pragma unroll
  for (int j = 0; j < T; ++j) {
    int sh = __shfl(idx_all, (jb + j) * 8 + g, 64);
    uint32_t c = ((jb + j) * 8 < rnd) ? (uint32_t)(sh & 0xffff) : dummy;
    hv[j] = *(const half8*)((const char*)ysg + (c << 7) + (sub << 4));
  }
  #pragma unroll
  for (int j = 0; j < T; ++j)
    #pragma unroll
    for (int k = 0; k < 8; ++k) acc[k] += (float)hv[j][k];
}

// Conv phase (R17 k_conv body, verbatim numerics), looped over virtual
// tiles vb = bid, bid+G, ... Trailing __syncthreads protects xp reuse.
template<int COUT, bool RELU, bool DROPN, bool WBF>
__device__ __forceinline__ void conv_phase(
    _Float16 (*xp)[136],
    const _Float16* __restrict__ yg, const _Float16* __restrict__ ysg,
    const int* __restrict__ cnt, const uint16_t* __restrict__ cs,
    const float* __restrict__ dis, const _Float16* __restrict__ wt,
    const float* __restrict__ b, float* __restrict__ outf,
    _Float16* __restrict__ outb, _Float16* __restrict__ outs,
    uint32_t nk0, uint32_t nk1, int n, int ntiles) {
  const int wave = threadIdx.x >> 6;
  const int t    = threadIdx.x & 63;
  const int g    = t >> 3;
  const int sub  = t & 7;
  const uint32_t dummy = (uint32_t)n;

  for (int vb = blockIdx.x; vb < ntiles; vb += (int)gridDim.x) {
    const int row0 = vb * 16;

    // ---- Phase 1 prologue: all 4 rows' loads issued up front ----
    int      idxs[4], ds4[4];
    float    dv4[4];
    _Float16 ygv[4];
    #pragma unroll
    for (int i = 0; i < 4; ++i) {
      int r = row0 + wave * 4 + i;
      r = r < n ? r : n - 1;
      idxs[i] = cs[(r << 6) + t];
      ds4[i]  = cnt[r];
      dv4[i]  = dis[r];
      ygv[i]  = yg[(uint32_t)(r << 6) + t];
    }

    // ---- Phase 1: per-row gather + butterfly reduction ----
    #pragma unroll
    for (int i = 0; i < 4; ++i) {
      const int cn  = ds4[i] < 64 ? ds4[i] : 64;
      const int rnd = (cn + 7) & ~7;
      float acc[8] = {0.f, 0.f, 0.f, 0.f, 0.f, 0.f, 0.f, 0.f};
      if (rnd <= 16) {
        gatherT<2>(idxs[i], rnd, 0, g, sub, ysg, dummy, acc);
      } else if (rnd <= 32) {
        gatherT<4>(idxs[i], rnd, 0, g, sub, ysg, dummy, acc);
      } else {
        gatherT<4>(idxs[i], rnd, 0, g, sub, ysg, dummy, acc);
        gatherT<4>(idxs[i], rnd, 4, g, sub, ysg, dummy, acc);
      }

      const bool b0 = (g & 1), b1 = (g & 2), b2 = (g & 4);
      float a4[4], a2[2], v;
      #pragma unroll
      for (int m = 0; m < 4; ++m) {
        float keep = b0 ? acc[2 * m + 1] : acc[2 * m];
        float send = b0 ? acc[2 * m]     : acc[2 * m + 1];
        a4[m] = keep + __shfl_xor(send, 8, 64);
      }
      #pragma unroll
      for (int m = 0; m < 2; ++m) {
        float keep = b1 ? a4[2 * m + 1] : a4[2 * m];
        float send = b1 ? a4[2 * m]     : a4[2 * m + 1];
        a2[m] = keep + __shfl_xor(send, 16, 64);
      }
      {
        float keep = b2 ? a2[1] : a2[0];
        float send = b2 ? a2[0] : a2[1];
        v = keep + __shfl_xor(send, 32, 64);
      }
      const int rl = wave * 4 + i;
      xp[rl][t]                  = ygv[i];
      xp[rl][64 + (sub * 8 + g)] = (_Float16)(-dv4[i] * v);
    }
    __syncthreads();

    // ---- Phase 2: MFMA (B fragments from global W^T) ----
    constexpr int NW = COUT / 16;
    const int nn   = t & 15;
    const int quad = t >> 4;
    if (wave < NW) {
      const int colg = wave * 16 + nn;
      float4v acc = {0.f, 0.f, 0.f, 0.f};
      #pragma unroll
      for (int ks = 0; ks < 4; ++ks) {
        half8 a  = *(const half8*)&xp[nn][quad * 8 + 32 * ks];
        half8 bb = *(const half8*)&wt[(size_t)colg * 128 + quad * 8 + 32 * ks];
        acc = __builtin_amdgcn_mfma_f32_16x16x32_f16(a, bb, acc, 0, 0, 0);
      }
      // ---- Phase 3: epilogue ----
      const float bias = b[colg];
      #pragma unroll
      for (int rg = 0; rg < 4; ++rg) {
        const int rl = quad * 4 + rg;
        const int rr = row0 + rl;
        if (rr < n) {
          float v = acc[rg] + bias;
          if (RELU) v = fmaxf(v, 0.0f);
          if (DROPN) {
            if (drop_keep(nk0, nk1, (uint32_t)(rr * 64 + colg))) v *= 2.5f;
            else v = 0.0f;
          }
          if (WBF) {
            outb[(size_t)rr * COUT + colg] = (_Float16)v;
            outs[(size_t)rr * COUT + colg] = (_Float16)(dis[rr] * v);
          } else {
            outf[(size_t)rr * COUT + colg] = v;
          }
        }
      }
    }
    __syncthreads();   // xp reused next virtual tile
  }
}

// R20: R19's persistent kernel with a SPILL-FREE register budget.
// R19 failed (939us) because __launch_bounds__(256,8) capped VGPR at 64 ->
// heavy scratch (FETCH+WRITE 352MB vs ~90MB working set, R1's signature).
// Change: __launch_bounds__(256,4) (cap 128) + grid 1024 = 4 blocks/CU x
// 256 CU -> co-residency still guaranteed (LDS 4.6KB, SGPR fine). R18
// showed conv is insensitive to 16-vs-32 waves/CU, so halved occupancy is
// free. 1024%8==0 keeps the fill phase's vb%8 == physical-XCD mapping.
__global__ __launch_bounds__(256, 4) void k_fused(
    const float* __restrict__ x, const int* __restrict__ row,
    const int* __restrict__ col,
    const float* __restrict__ W0, const float* __restrict__ b0,
    const float* __restrict__ W1, const float* __restrict__ b1,
    const float* __restrict__ W2, const float* __restrict__ b2,
    unsigned* __restrict__ bars, int* __restrict__ cnt,
    float* __restrict__ dis, uint16_t* __restrict__ cs,
    _Float16* __restrict__ ya, _Float16* __restrict__ ysa,
    _Float16* __restrict__ yb, _Float16* __restrict__ ysb,
    _Float16* __restrict__ wh, float* __restrict__ out,
    uint32_t dk00, uint32_t dk01, uint32_t dk10, uint32_t dk11,
    uint32_t dk20, uint32_t dk21, int n, int e) {
  __shared__ __align__(16) _Float16 xp[16][136];
  const int tid  = threadIdx.x;
  const int bid  = blockIdx.x;
  const int G    = (int)gridDim.x;
  const int gtid = bid * 256 + tid;
  const unsigned tgt = gridDim.x;

  // ---- P0 (no deps; overlaps fill): W -> f16 W^T + zero dummy gather rows
  if (gtid < 20480) {
    int d = gtid;
    if (d < 8192) {
      int o = d >> 7, k = d & 127;
      wh[d] = (_Float16)W0[k * 64 + o];
    } else if (d < 16384) {
      int d1 = d - 8192, o = d1 >> 7, k = d1 & 127;
      wh[d] = (_Float16)W1[k * 64 + o];
    } else {
      int d2 = d - 16384, o = d2 >> 7, k = d2 & 127;
      wh[d] = (_Float16)W2[k * 32 + o];
    }
  }
  if (gtid < 64) {
    ysa[((size_t)n << 6) + gtid] = (_Float16)0.f;
    ysb[((size_t)n << 6) + gtid] = (_Float16)0.f;
  }

  // ---- P1: XCD-owned slotted-CSR fill (cnt zeroed by host memsetAsync)
  {
    const int rpx = (n + 7) / 8;
    const int nc8 = ((e + 255) >> 8) * 8;
    for (int vb = bid; vb < nc8; vb += G) {
      const int owner = vb & 7;                 // == physical XCD (G%8==0)
      const int i = (vb >> 3) * 256 + tid;
      if (i < e) {
        int r = row[i];
        if (r / rpx == owner) {
          int pos = atomicAdd(&cnt[r], 1);
          if (pos < 64) cs[(r << 6) + pos] = (uint16_t)col[i];
        }
      }
    }
  }
  grid_bar(&bars[0], tgt);

  // ---- P2: layer-0 dropout + dis + slot padding
  {
    const int nd = n * 64;
    for (int i = gtid; i < nd; i += G * 256) {
      const int r  = i >> 6;
      const int t2 = i & 63;
      const int d  = cnt[r];
      const float dis_r = (d > 0) ? rsqrtf((float)d) : 0.0f;
      float v = drop_keep(dk00, dk01, (uint32_t)i) ? x[i] * 2.5f : 0.0f;
      ya[i]  = (_Float16)v;
      ysa[i] = (_Float16)(dis_r * v);
      if (t2 == 0) dis[r] = dis_r;
      const int cn  = d < 64 ? d : 64;
      const int rnd = (cn + 7) & ~7;
      if (t2 >= cn && t2 < rnd) cs[(r << 6) + t2] = (uint16_t)n;
    }
  }
  grid_bar(&bars[1], tgt);

  // ---- P3..P5: the three conv layers
  const int ntiles = (n + 15) / 16;
  conv_phase<64, true,  true,  true >(xp, ya, ysa, cnt, cs, dis, wh, b0,
                                      nullptr, yb, ysb, dk10, dk11, n, ntiles);
  grid_bar(&bars[2], tgt);
  conv_phase<64, true,  true,  true >(xp, yb, ysb, cnt, cs, dis, wh + 8192, b1,
                                      nullptr, ya, ysa, dk20, dk21, n, ntiles);
  grid_bar(&bars[3], tgt);
  conv_phase<32, false, false, false>(xp, ya, ysa, cnt, cs, dis, wh + 16384, b2,
                                      out, nullptr, nullptr, 0u, 0u, n, ntiles);
}

extern "C" void kernel_launch(void* const* d_in, const int* in_sizes, int n_in,
                              void* d_out, int out_size, void* d_ws, size_t ws_size,
                              hipStream_t stream) {
  const float* x   = (const float*)d_in[0];
  const int*   ei  = (const int*)d_in[1];
  const float* W0  = (const float*)d_in[2];
  const float* b0  = (const float*)d_in[3];
  const float* W1f = (const float*)d_in[4];
  const float* b1  = (const float*)d_in[5];
  const float* W2  = (const float*)d_in[6];
  const float* b2  = (const float*)d_in[7];
  float* out = (float*)d_out;

  const int n = in_sizes[0] / 64;   // 50000
  const int e = in_sizes[1] / 2;    // 800000
  const int* row = ei;
  const int* col = ei + e;

  size_t off = 0;
  auto carve = [&](size_t elems) {   // elems in int32 units, 1KB-aligned
    size_t o = off;
    off += (elems + 255) & ~(size_t)255;
    return o;
  };
  int* base = (int*)d_ws;
  unsigned* bars = (unsigned*)(base + carve(8));                   // [0,256) ints
  int*      cnt  = base + carve(n);                                // at 256
  float*    dis  = (float*)(base + carve(n));
  uint16_t* cs   = (uint16_t*)(base + carve((size_t)n * 32));      // n*64 u16
  _Float16* ya   = (_Float16*)(base + carve((size_t)n * 32));      // n*64 f16
  _Float16* ysa  = (_Float16*)(base + carve((size_t)(n + 1) * 32));
  _Float16* yb   = (_Float16*)(base + carve((size_t)n * 32));
  _Float16* ysb  = (_Float16*)(base + carve((size_t)(n + 1) * 32));
  _Float16* wh   = (_Float16*)(base + carve(10240));               // 20480 f16
  (void)ws_size;

  // dropout keys: fold_in(jax.random.key(1), i) = threefry2x32([0,1],[0,i])
  uint32_t dk[3][2];
  for (uint32_t i = 0; i < 3; ++i) tf2x32(0u, 1u, 0u, i, &dk[i][0], &dk[i][1]);

  // zero barrier counters (first 1KB) AND cnt in one contiguous memset
  hipMemsetAsync(base, 0, (size_t)(256 + n) * 4, stream);

  const int G = 1024;   // 4 blocks/CU x 256 CU co-resident; %8==0
  k_fused<<<G, 256, 0, stream>>>(x, row, col, W0, b0, W1f, b1, W2, b2,
                                 bars, cnt, dis, cs, ya, ysa, yb, ysb, wh, out,
                                 dk[0][0], dk[0][1], dk[1][0], dk[1][1],
                                 dk[2][0], dk[2][1], n, e);
}

// Round 7
// 188.922 us; speedup vs baseline: 5.0647x; 4.0715x over previous
//
#include <hip/hip_runtime.h>
#include <stdint.h>

typedef _Float16 half8 __attribute__((ext_vector_type(8)));
typedef float float4v __attribute__((ext_vector_type(4)));

__host__ __device__ inline void tf2x32(uint32_t k0, uint32_t k1,
                                       uint32_t x0, uint32_t x1,
                                       uint32_t* o0, uint32_t* o1) {
  const uint32_t ks2 = k0 ^ k1 ^ 0x1BD11BDAu;
#define ROTL(v, s) (((v) << (s)) | ((v) >> (32 - (s))))
#define RND(r) do { x0 += x1; x1 = ROTL(x1, r); x1 ^= x0; } while (0)
  x0 += k0; x1 += k1;
  RND(13); RND(15); RND(26); RND(6);
  x0 += k1; x1 += ks2 + 1u;
  RND(17); RND(29); RND(16); RND(24);
  x0 += ks2; x1 += k0 + 2u;
  RND(13); RND(15); RND(26); RND(6);
  x0 += k0; x1 += k1 + 3u;
  RND(17); RND(29); RND(16); RND(24);
  x0 += k1; x1 += ks2 + 4u;
  RND(13); RND(15); RND(26); RND(6);
  x0 += ks2; x1 += k0 + 5u;
  *o0 = x0; *o1 = x1;
#undef RND
#undef ROTL
}

__device__ inline bool drop_keep(uint32_t k0, uint32_t k1, uint32_t idx) {
  uint32_t o0, o1;
  tf2x32(k0, k1, 0u, idx, &o0, &o1);
  uint32_t bits = o0 ^ o1;
  float u = __uint_as_float((bits >> 9) | 0x3f800000u) - 1.0f;
  return u < 0.4f;
}

// XCD-owned slotted-CSR fill (R9-proven).
__global__ void k_fill2(const int* __restrict__ row, const int* __restrict__ col,
                        int* __restrict__ cnt, uint16_t* __restrict__ cs,
                        int e, int rows_per_xcd) {
  const int owner = blockIdx.x & 7;
  const int i = (blockIdx.x >> 3) * 256 + threadIdx.x;
  if (i < e) {
    int r = row[i];
    if (r / rows_per_xcd == owner) {
      int pos = atomicAdd(&cnt[r], 1);
      if (pos < 64) cs[(r << 6) + pos] = (uint16_t)col[i];
    }
  }
}

// layer-0 dropout + dis + slot padding (to multiple of 8) + W -> f16 W^T.
__global__ void k_drop(const float* __restrict__ x, const int* __restrict__ cnt,
                       uint16_t* __restrict__ cs, float* __restrict__ dis,
                       _Float16* __restrict__ y, _Float16* __restrict__ ys,
                       _Float16* __restrict__ ysb, uint32_t k0, uint32_t k1,
                       int n, int nd,
                       const float* __restrict__ W0, const float* __restrict__ W1,
                       const float* __restrict__ W2, _Float16* __restrict__ wh) {
  int i = blockIdx.x * 256 + threadIdx.x;
  if (i < 20480) {
    int d = i;
    if (d < 8192) {
      int o = d >> 7, k = d & 127;
      wh[d] = (_Float16)W0[k * 64 + o];
    } else if (d < 16384) {
      int d1 = d - 8192, o = d1 >> 7, k = d1 & 127;
      wh[d] = (_Float16)W1[k * 64 + o];
    } else {
      int d2 = d - 16384, o = d2 >> 7, k = d2 & 127;
      wh[d] = (_Float16)W2[k * 32 + o];
    }
  }
  if (i < 64) {                        // zero dummy gather rows (index n)
    ys[((size_t)n << 6) + i]  = (_Float16)0.f;
    ysb[((size_t)n << 6) + i] = (_Float16)0.f;
  }
  if (i < nd) {
    const int r = i >> 6;
    const int t = i & 63;
    const int d = cnt[r];
    const float dis_r = (d > 0) ? rsqrtf((float)d) : 0.0f;
    float v = drop_keep(k0, k1, (uint32_t)i) ? x[i] * 2.5f : 0.0f;
    y[i]  = (_Float16)v;
    ys[i] = (_Float16)(dis_r * v);
    if (t == 0) dis[r] = dis_r;
    const int cn = d < 64 ? d : 64;
    const int rnd = (cn + 7) & ~7;
    if (t >= cn && t < rnd) cs[(r << 6) + t] = (uint16_t)n;  // pad slot
  }
}

// T batches of 8 edges; ALL gathers issued before any consumption.
// Lane l = 8*g + sub loads bytes [sub*16, sub*16+16) of edge g's row.
template<int T>
__device__ __forceinline__ void gatherT(int idx_all, int rnd, int g, int sub,
                                        const _Float16* __restrict__ ysg,
                                        uint32_t dummy, float acc[8]) {
  half8 hv[T];
  #pragma unroll
  for (int j = 0; j < T; ++j) {
    int sh = __shfl(idx_all, j * 8 + g, 64);          // slot (j*8+g)'s index
    uint32_t c = (j * 8 < rnd) ? (uint32_t)(sh & 0xffff) : dummy;  // uniform sel
    hv[j] = *(const half8*)((const char*)ysg + (c << 7) + (sub << 4));
  }
  #pragma unroll
  for (int j = 0; j < T; ++j)
    #pragma unroll
    for (int k = 0; k < 8; ++k) acc[k] += (float)hv[j][k];
}

// Fused conv. Block = 4 waves, 16 rows (50000 = 3125*16 exact).
// Phase 1: 8-edges-per-dwordx4 gather (R14-proven) with (a) all 4 rows'
//   prologue loads (cs line, cnt, dis, y-row) HOISTED and issued together,
//   (b) per-row reduction via a 3-step shfl_xor halving butterfly (keep/send
//   cndmask pairs -> fixed register result, no runtime-indexed arrays, no LDS,
//   no barriers). Lane t ends with feature (t&7)*8+(t>>3)'s full sum and
//   writes that permuted xp column (covers 0..63, 2 lanes/bank = free).
// Phase 2: MFMA 16x16x32_f16; A = [y|p] LDS tile, B = global f16 W^T.
// Phase 3: epilogue: +bias, relu, next-layer dropout; dual store y / ys.
template<int COUT, bool RELU, bool DROPN, bool WBF>
__global__ __launch_bounds__(256, 6) void k_conv(
    const _Float16* __restrict__ yg, const _Float16* __restrict__ ysg,
    const int* __restrict__ cnt, const uint16_t* __restrict__ cs,
    const float* __restrict__ dis, const _Float16* __restrict__ wt,
    const float* __restrict__ b, float* __restrict__ outf,
    _Float16* __restrict__ outb, _Float16* __restrict__ outs,
    uint32_t nk0, uint32_t nk1, int n) {
  constexpr int R  = 16;
  constexpr int TS = 136;
  __shared__ __align__(16) _Float16 xp[R][TS];

  const int wave = threadIdx.x >> 6;
  const int t    = threadIdx.x & 63;
  const int row0 = blockIdx.x * R;
  const int g    = t >> 3;
  const int sub  = t & 7;
  const uint32_t dummy = (uint32_t)n;

  // ---- Phase 1 prologue: all 4 rows' loads issued up front ----
  int      idxs[4], ds4[4];
  float    dv4[4];
  _Float16 ygv[4];
  #pragma unroll
  for (int i = 0; i < 4; ++i) {
    int r = row0 + wave * 4 + i;
    r = r < n ? r : n - 1;                       // clamp (grid is exact anyway)
    idxs[i] = cs[(r << 6) + t];                  // coalesced 128B slot line
    ds4[i]  = cnt[r];                            // wave-uniform
    dv4[i]  = dis[r];
    ygv[i]  = yg[(uint32_t)(r << 6) + t];
  }

  // ---- Phase 1: per-row gather + butterfly reduction ----
  #pragma unroll
  for (int i = 0; i < 4; ++i) {
    const int cn  = ds4[i] < 64 ? ds4[i] : 64;
    const int rnd = (cn + 7) & ~7;
    float acc[8] = {0.f, 0.f, 0.f, 0.f, 0.f, 0.f, 0.f, 0.f};
    if (rnd <= 16)      gatherT<2>(idxs[i], rnd, g, sub, ysg, dummy, acc);
    else if (rnd <= 32) gatherT<4>(idxs[i], rnd, g, sub, ysg, dummy, acc);
    else                gatherT<8>(idxs[i], rnd, g, sub, ysg, dummy, acc);

    // halving butterfly over g bits (lane bits 3..5): lane ends with the
    // full sum of acc element g. keep/send selected by g's bit per step.
    const bool b0 = (g & 1), b1 = (g & 2), b2 = (g & 4);
    float a4[4], a2[2], v;
    #pragma unroll
    for (int m = 0; m < 4; ++m) {
      float keep = b0 ? acc[2 * m + 1] : acc[2 * m];
      float send = b0 ? acc[2 * m]     : acc[2 * m + 1];
      a4[m] = keep + __shfl_xor(send, 8, 64);
    }
    #pragma unroll
    for (int m = 0; m < 2; ++m) {
      float keep = b1 ? a4[2 * m + 1] : a4[2 * m];
      float send = b1 ? a4[2 * m]     : a4[2 * m + 1];
      a2[m] = keep + __shfl_xor(send, 16, 64);
    }
    {
      float keep = b2 ? a2[1] : a2[0];
      float send = b2 ? a2[0] : a2[1];
      v = keep + __shfl_xor(send, 32, 64);
    }
    const int rl = wave * 4 + i;
    xp[rl][t]                    = ygv[i];
    xp[rl][64 + (sub * 8 + g)]   = (_Float16)(-dv4[i] * v);
  }
  __syncthreads();

  // ---- Phase 2: MFMA (B fragments from global W^T) ----
  constexpr int NW = COUT / 16;
  const int nn   = t & 15;
  const int quad = t >> 4;
  if (wave < NW) {
    const int colg = wave * 16 + nn;
    float4v acc = {0.f, 0.f, 0.f, 0.f};
    #pragma unroll
    for (int ks = 0; ks < 4; ++ks) {
      half8 a  = *(const half8*)&xp[nn][quad * 8 + 32 * ks];
      half8 bb = *(const half8*)&wt[(size_t)colg * 128 + quad * 8 + 32 * ks];
      acc = __builtin_amdgcn_mfma_f32_16x16x32_f16(a, bb, acc, 0, 0, 0);
    }
    // ---- Phase 3: epilogue ----
    const float bias = b[colg];
    #pragma unroll
    for (int rg = 0; rg < 4; ++rg) {
      const int rl = quad * 4 + rg;
      const int rr = row0 + rl;
      if (rr < n) {
        float v = acc[rg] + bias;
        if (RELU) v = fmaxf(v, 0.0f);
        if (DROPN) {
          if (drop_keep(nk0, nk1, (uint32_t)(rr * 64 + colg))) v *= 2.5f;
          else v = 0.0f;
        }
        if (WBF) {
          outb[(size_t)rr * COUT + colg] = (_Float16)v;
          outs[(size_t)rr * COUT + colg] = (_Float16)(dis[rr] * v);
        } else {
          outf[(size_t)rr * COUT + colg] = v;
        }
      }
    }
  }
}

extern "C" void kernel_launch(void* const* d_in, const int* in_sizes, int n_in,
                              void* d_out, int out_size, void* d_ws, size_t ws_size,
                              hipStream_t stream) {
  const float* x   = (const float*)d_in[0];
  const int*   ei  = (const int*)d_in[1];
  const float* W0  = (const float*)d_in[2];
  const float* b0  = (const float*)d_in[3];
  const float* W1f = (const float*)d_in[4];
  const float* b1  = (const float*)d_in[5];
  const float* W2  = (const float*)d_in[6];
  const float* b2  = (const float*)d_in[7];
  float* out = (float*)d_out;

  const int n = in_sizes[0] / 64;   // 50000
  const int e = in_sizes[1] / 2;    // 800000
  const int* row = ei;
  const int* col = ei + e;

  size_t off = 0;
  auto carve = [&](size_t elems) {   // elems in int32 units, 1KB-aligned
    size_t o = off;
    off += (elems + 255) & ~(size_t)255;
    return o;
  };
  int* base = (int*)d_ws;
  int*      cnt = base + carve(n);
  float*    dis = (float*)(base + carve(n));
  uint16_t* cs  = (uint16_t*)(base + carve((size_t)n * 32));       // n*64 u16
  _Float16* ya  = (_Float16*)(base + carve((size_t)n * 32));       // n*64 f16
  _Float16* ysa = (_Float16*)(base + carve((size_t)(n + 1) * 32)); // (n+1)*64 f16
  _Float16* yb  = (_Float16*)(base + carve((size_t)n * 32));
  _Float16* ysb = (_Float16*)(base + carve((size_t)(n + 1) * 32));
  _Float16* wh  = (_Float16*)(base + carve(10240));                // 20480 f16
  (void)ws_size;
  _Float16* wh0 = wh;            // [64][128]
  _Float16* wh1 = wh + 8192;     // [64][128]
  _Float16* wh2 = wh + 16384;    // [32][128]

  // dropout keys: fold_in(jax.random.key(1), i) = threefry2x32([0,1],[0,i])
  uint32_t dk[3][2];
  for (uint32_t i = 0; i < 3; ++i) tf2x32(0u, 1u, 0u, i, &dk[i][0], &dk[i][1]);

  hipMemsetAsync(cnt, 0, (size_t)n * 4, stream);

  const int nchunk = (e + 255) / 256;    // 3125
  const int bd = ((n * 64) + 255) / 256; // 12500
  const int bc = (n + 15) / 16;          // 3125
  const int rpx = (n + 7) / 8;           // rows per XCD slice (6250)

  k_fill2<<<nchunk * 8, 256, 0, stream>>>(row, col, cnt, cs, e, rpx);
  k_drop<<<bd, 256, 0, stream>>>(x, cnt, cs, dis, ya, ysa, ysb,
                                 dk[0][0], dk[0][1], n, n * 64,
                                 W0, W1f, W2, wh);

  k_conv<64, true,  true,  true ><<<bc, 256, 0, stream>>>(
      ya, ysa, cnt, cs, dis, wh0, b0, nullptr, yb, ysb, dk[1][0], dk[1][1], n);
  k_conv<64, true,  true,  true ><<<bc, 256, 0, stream>>>(
      yb, ysb, cnt, cs, dis, wh1, b1, nullptr, ya, ysa, dk[2][0], dk[2][1], n);
  k_conv<32, false, false, false><<<bc, 256, 0, stream>>>(
      ya, ysa, cnt, cs, dis, wh2, b2, out, nullptr, nullptr, 0u, 0u, n);
}